// Round 1
// baseline (233.306 us; speedup 1.0000x reference)
//
#include <hip/hip_runtime.h>
#include <math.h>

#define N_PTS   131072
#define EPOCHS  1000
#define EPAD    1024
#define THRESH2 100.0f   // dis <= 10  <=>  dis^2 <= 100

// ---------------- workspace layout ----------------
// [0,      16384)  : float4 H[EPAD]      (c, s, u, v) per hypothesis
// [16384,  20480)  : int    counts[EPAD]
// [20480,  20496)  : float4 best         (c, s, u, v) of best hypothesis
// [20496,  20532)  : float  acc[9]       refit raw moments
//   acc: 0=Sw 1=SxA 2=SyA 3=SxB 4=SyB 5=SxAxB 6=SxAyB 7=SyAxB 8=SyAyB

// Kernel 1: one thread per epoch — 5-point rigid fit. Also zero-inits counts.
__global__ void hypo_kernel(const float* __restrict__ A, const float* __restrict__ B,
                            const int* __restrict__ idx,
                            float4* __restrict__ H, int* __restrict__ counts) {
    int e = blockIdx.x * blockDim.x + threadIdx.x;
    if (e >= EPAD) return;
    if (e >= EPOCHS) { counts[e] = -1; return; }   // padded slots never win argmax
    counts[e] = 0;

    float ax[5], ay[5], bx[5], by[5];
    float cAx = 0.f, cAy = 0.f, cBx = 0.f, cBy = 0.f;
#pragma unroll
    for (int j = 0; j < 5; ++j) {
        int p = idx[e * 5 + j];
        ax[j] = A[2 * p];     ay[j] = A[2 * p + 1];
        bx[j] = B[2 * p];     by[j] = B[2 * p + 1];
        cAx += ax[j]; cAy += ay[j];
        cBx += bx[j]; cBy += by[j];
    }
    cAx /= 5.0f; cAy /= 5.0f; cBx /= 5.0f; cBy /= 5.0f;

    float sxx = 0.f, sxy = 0.f;
#pragma unroll
    for (int j = 0; j < 5; ++j) {
        float a0x = ax[j] - cAx, a0y = ay[j] - cAy;
        float b0x = bx[j] - cBx, b0y = by[j] - cBy;
        sxx += a0x * b0x + a0y * b0y;
        sxy += a0x * b0y - a0y * b0x;
    }
    float rot = atan2f(sxy, sxx);
    float s, c;
    sincosf(rot, &s, &c);
    float u = cBx - (c * cAx - s * cAy);
    float v = cBy - (s * cAx + c * cAy);
    H[e] = make_float4(c, s, u, v);
}

// Kernel 2: scoring. thread = hypothesis (grid.x chunks of 256),
// grid.y = point chunks; point tiles staged in LDS, broadcast-read.
#define TILE 256
__global__ void score_kernel(const float* __restrict__ A, const float* __restrict__ B,
                             const float4* __restrict__ H, int* __restrict__ counts,
                             int pts_per_chunk) {
    __shared__ float4 pts[TILE];
    int e = blockIdx.x * TILE + threadIdx.x;       // e < EPAD by construction
    float4 h = H[e];                               // garbage for e>=EPOCHS, never stored
    float c = h.x, s = h.y, u = h.z, v = h.w;

    int p0 = blockIdx.y * pts_per_chunk;
    int cnt = 0;
    for (int t = 0; t < pts_per_chunk; t += TILE) {
        int pi = p0 + t + threadIdx.x;
        float2 a = ((const float2*)A)[pi];
        float2 b = ((const float2*)B)[pi];
        __syncthreads();                           // previous tile fully consumed
        pts[threadIdx.x] = make_float4(a.x, a.y, b.x, b.y);
        __syncthreads();
#pragma unroll 8
        for (int k = 0; k < TILE; ++k) {
            float4 p = pts[k];                     // uniform addr -> LDS broadcast
            float ex = p.z - fmaf(c, p.x, fmaf(-s, p.y, u));
            float ey = p.w - fmaf(s, p.x, fmaf(c, p.y, v));
            float d2 = fmaf(ex, ex, ey * ey);
            cnt += (d2 <= THRESH2) ? 1 : 0;
        }
    }
    if (e < EPOCHS) atomicAdd(&counts[e], cnt);
}

// Kernel 3: argmax (first-index tie-break, matching jnp.argmax), write E_best,
// stash best params, zero refit accumulators.
__global__ void argmax_kernel(const int* __restrict__ counts, const float4* __restrict__ H,
                              float* __restrict__ out, float4* __restrict__ best,
                              float* __restrict__ acc) {
    __shared__ int scnt[256];
    __shared__ int sidx[256];
    int tid = threadIdx.x;
    int bc = -2, bi = 0;
    for (int e = tid; e < EPAD; e += 256) {        // increasing order: '>' keeps first
        int cv = counts[e];
        if (cv > bc) { bc = cv; bi = e; }
    }
    scnt[tid] = bc; sidx[tid] = bi;
    __syncthreads();
    for (int s2 = 128; s2 > 0; s2 >>= 1) {
        if (tid < s2) {
            int c2 = scnt[tid + s2], i2 = sidx[tid + s2];
            if (c2 > scnt[tid] || (c2 == scnt[tid] && i2 < sidx[tid])) {
                scnt[tid] = c2; sidx[tid] = i2;
            }
        }
        __syncthreads();
    }
    if (tid == 0) {
        float4 h = H[sidx[0]];
        *best = h;
        out[9]  = h.x;  out[10] = -h.y; out[11] = h.z;
        out[12] = h.y;  out[13] = h.x;  out[14] = h.w;
        out[15] = 0.f;  out[16] = 0.f;  out[17] = 1.f;
    }
    if (tid < 9) acc[tid] = 0.f;
}

// Kernel 4: refit raw moments over all N points, weights = inlier mask of best.
__global__ void refit_kernel(const float* __restrict__ A, const float* __restrict__ B,
                             const float4* __restrict__ bestp, float* __restrict__ acc) {
    float4 h = *bestp;
    float c = h.x, s = h.y, u = h.z, v = h.w;
    float Sw = 0.f, SxA = 0.f, SyA = 0.f, SxB = 0.f, SyB = 0.f;
    float Sxx = 0.f, Sxy = 0.f, Syx = 0.f, Syy = 0.f;
    int stride = gridDim.x * blockDim.x;
    for (int i = blockIdx.x * blockDim.x + threadIdx.x; i < N_PTS; i += stride) {
        float2 a = ((const float2*)A)[i];
        float2 b = ((const float2*)B)[i];
        float ex = b.x - fmaf(c, a.x, fmaf(-s, a.y, u));
        float ey = b.y - fmaf(s, a.x, fmaf(c, a.y, v));
        float d2 = fmaf(ex, ex, ey * ey);
        if (d2 <= THRESH2) {
            Sw += 1.f;
            SxA += a.x; SyA += a.y; SxB += b.x; SyB += b.y;
            Sxx += a.x * b.x; Sxy += a.x * b.y;
            Syx += a.y * b.x; Syy += a.y * b.y;
        }
    }
#pragma unroll
    for (int off = 32; off > 0; off >>= 1) {
        Sw  += __shfl_down(Sw,  off);
        SxA += __shfl_down(SxA, off); SyA += __shfl_down(SyA, off);
        SxB += __shfl_down(SxB, off); SyB += __shfl_down(SyB, off);
        Sxx += __shfl_down(Sxx, off); Sxy += __shfl_down(Sxy, off);
        Syx += __shfl_down(Syx, off); Syy += __shfl_down(Syy, off);
    }
    if ((threadIdx.x & 63) == 0) {
        atomicAdd(&acc[0], Sw);
        atomicAdd(&acc[1], SxA); atomicAdd(&acc[2], SyA);
        atomicAdd(&acc[3], SxB); atomicAdd(&acc[4], SyB);
        atomicAdd(&acc[5], Sxx); atomicAdd(&acc[6], Sxy);
        atomicAdd(&acc[7], Syx); atomicAdd(&acc[8], Syy);
    }
}

// Kernel 5: finalize E_final from raw moments.
__global__ void finalize_kernel(const float* __restrict__ acc, float* __restrict__ out) {
    if (threadIdx.x == 0) {
        float Sw = acc[0];
        float ws = fmaxf(Sw, 1e-8f);
        float cAx = acc[1] / ws, cAy = acc[2] / ws;
        float cBx = acc[3] / ws, cBy = acc[4] / ws;
        // centered-sum identities
        float sxx = (acc[5] - ws * cAx * cBx) + (acc[8] - ws * cAy * cBy);
        float sxy = (acc[6] - ws * cAx * cBy) - (acc[7] - ws * cAy * cBx);
        float rot = atan2f(sxy, sxx);
        float s, c;
        sincosf(rot, &s, &c);
        float u = cBx - (c * cAx - s * cAy);
        float v = cBy - (s * cAx + c * cAy);
        out[0] = c;   out[1] = -s;  out[2] = u;
        out[3] = s;   out[4] = c;   out[5] = v;
        out[6] = 0.f; out[7] = 0.f; out[8] = 1.f;
    }
}

extern "C" void kernel_launch(void* const* d_in, const int* in_sizes, int n_in,
                              void* d_out, int out_size, void* d_ws, size_t ws_size,
                              hipStream_t stream) {
    const float* A  = (const float*)d_in[0];   // pstA [1,N,2]
    const float* B  = (const float*)d_in[1];   // pstB [1,N,2]
    const int* sidx = (const int*)d_in[2];     // subset_idx [EPOCHS,5]
    float* out = (float*)d_out;

    char* ws = (char*)d_ws;
    float4* H      = (float4*)(ws);
    int*    counts = (int*)(ws + 16384);
    float4* best   = (float4*)(ws + 20480);
    float*  acc    = (float*)(ws + 20496);

    hypo_kernel<<<EPAD / 256, 256, 0, stream>>>(A, B, sidx, H, counts);

    dim3 g2(EPAD / TILE, 128);                 // 4 hypothesis chunks x 128 point chunks
    score_kernel<<<g2, TILE, 0, stream>>>(A, B, H, counts, N_PTS / 128);

    argmax_kernel<<<1, 256, 0, stream>>>(counts, H, out, best, acc);

    refit_kernel<<<256, 256, 0, stream>>>(A, B, best, acc);

    finalize_kernel<<<1, 64, 0, stream>>>(acc, out);
}

// Round 3
// 131.163 us; speedup vs baseline: 1.7788x; 1.7788x over previous
//
#include <hip/hip_runtime.h>
#include <math.h>

#define N_PTS   131072
#define EPOCHS  1000
#define EPAD    1024
#define THRESH2 100.0f   // dis <= 10  <=>  dis^2 <= 100

#define SC_CHUNKS  256
#define SC_PTS     (N_PTS / SC_CHUNKS)     // 512 points per chunk
#define SC_THREADS 512                     // 2 hypotheses per thread

#define RF_BLOCKS  64
#define RF_THREADS 256
#define RF_PTS     (N_PTS / (RF_BLOCKS * RF_THREADS))  // 8 points per thread

// ---------------- workspace layout (all offsets in bytes) ----------------
// H        float4[1024]        @ 0         (16384)
// partial  int[256][1024]      @ 16384     (1048576)
// counts   int[1024]           @ 1064960   (4096)
// best     float4              @ 1069056   (16)
// rpart    float[64][16]       @ 1069072   (4096)   refit per-block partials
#define OFF_H       0
#define OFF_PARTIAL 16384
#define OFF_COUNTS  1064960
#define OFF_BEST    1069056
#define OFF_RPART   1069072

// Kernel 1: one thread per epoch — 5-point rigid fit.
__global__ void hypo_kernel(const float* __restrict__ A, const float* __restrict__ B,
                            const int* __restrict__ idx, float4* __restrict__ H) {
    int e = blockIdx.x * blockDim.x + threadIdx.x;
    if (e >= EPOCHS) return;

    float ax[5], ay[5], bx[5], by[5];
    float cAx = 0.f, cAy = 0.f, cBx = 0.f, cBy = 0.f;
#pragma unroll
    for (int j = 0; j < 5; ++j) {
        int p = idx[e * 5 + j];
        ax[j] = A[2 * p];     ay[j] = A[2 * p + 1];
        bx[j] = B[2 * p];     by[j] = B[2 * p + 1];
        cAx += ax[j]; cAy += ay[j];
        cBx += bx[j]; cBy += by[j];
    }
    cAx *= 0.2f; cAy *= 0.2f; cBx *= 0.2f; cBy *= 0.2f;

    float sxx = 0.f, sxy = 0.f;
#pragma unroll
    for (int j = 0; j < 5; ++j) {
        float a0x = ax[j] - cAx, a0y = ay[j] - cAy;
        float b0x = bx[j] - cBx, b0y = by[j] - cBy;
        sxx += a0x * b0x + a0y * b0y;
        sxy += a0x * b0y - a0y * b0x;
    }
    float rot = atan2f(sxy, sxx);
    float s, c;
    sincosf(rot, &s, &c);
    float u = cBx - (c * cAx - s * cAy);
    float v = cBy - (s * cAx + c * cAy);
    H[e] = make_float4(c, s, u, v);
}

// Kernel 2: scoring. Thread t owns hypotheses t and t+512 (registers).
// Points are wave-uniform -> scalar (SMEM) loads; no LDS, no atomics.
// Writes partial counts [chunk][e].
__global__ __launch_bounds__(SC_THREADS) void score_kernel(
        const float* __restrict__ A, const float* __restrict__ B,
        const float4* __restrict__ H, int* __restrict__ partial) {
    int tid = threadIdx.x;
    int chunk = blockIdx.x;
    float4 h0 = H[tid];
    float4 h1 = H[tid + SC_THREADS];
    int c0 = 0, c1 = 0;

    int p0 = chunk * SC_PTS;
    for (int t = 0; t < SC_PTS; t += 4) {
        int p = p0 + t;                          // uniform across the block
        float2 pa[4], pb[4];
#pragma unroll
        for (int j = 0; j < 4; ++j) {
            pa[j] = ((const float2*)A)[p + j];
            pb[j] = ((const float2*)B)[p + j];
        }
#pragma unroll
        for (int j = 0; j < 4; ++j) {
            float ax = pa[j].x, ay = pa[j].y;
            float bx = pb[j].x, by = pb[j].y;
            {
                float ex = fmaf(-h0.x, ax, fmaf(h0.y, ay, bx - h0.z));
                float ey = fmaf(-h0.x, ay, fmaf(-h0.y, ax, by - h0.w));
                float d2 = fmaf(ex, ex, ey * ey);
                c0 += (d2 <= THRESH2) ? 1 : 0;
            }
            {
                float ex = fmaf(-h1.x, ax, fmaf(h1.y, ay, bx - h1.z));
                float ey = fmaf(-h1.x, ay, fmaf(-h1.y, ax, by - h1.w));
                float d2 = fmaf(ex, ex, ey * ey);
                c1 += (d2 <= THRESH2) ? 1 : 0;
            }
        }
    }
    partial[chunk * EPAD + tid] = c0;
    partial[chunk * EPAD + tid + SC_THREADS] = c1;
}

// Kernel 3: sum partial counts per hypothesis (coalesced, deterministic).
__global__ void reduce_counts_kernel(const int* __restrict__ partial,
                                     int* __restrict__ counts) {
    int e = blockIdx.x * blockDim.x + threadIdx.x;   // 4 x 256 = 1024
    int s = 0;
    for (int ch = 0; ch < SC_CHUNKS; ++ch) s += partial[ch * EPAD + e];
    counts[e] = (e < EPOCHS) ? s : -1;               // padded slots never win
}

// Kernel 4: argmax (first-index tie-break == jnp.argmax), emit E_best, stash best.
__global__ void argmax_kernel(const int* __restrict__ counts, const float4* __restrict__ H,
                              float* __restrict__ out, float4* __restrict__ best) {
    __shared__ int scnt[256];
    __shared__ int sidx[256];
    int tid = threadIdx.x;
    int bc = -2, bi = 0;
    for (int e = tid; e < EPAD; e += 256) {          // increasing order: '>' keeps first
        int cv = counts[e];
        if (cv > bc) { bc = cv; bi = e; }
    }
    scnt[tid] = bc; sidx[tid] = bi;
    __syncthreads();
    for (int s2 = 128; s2 > 0; s2 >>= 1) {
        if (tid < s2) {
            int c2 = scnt[tid + s2], i2 = sidx[tid + s2];
            if (c2 > scnt[tid] || (c2 == scnt[tid] && i2 < sidx[tid])) {
                scnt[tid] = c2; sidx[tid] = i2;
            }
        }
        __syncthreads();
    }
    if (tid == 0) {
        float4 h = H[sidx[0]];
        *best = h;
        out[9]  = h.x;  out[10] = -h.y; out[11] = h.z;
        out[12] = h.y;  out[13] = h.x;  out[14] = h.w;
        out[15] = 0.f;  out[16] = 0.f;  out[17] = 1.f;
    }
}

// Kernel 5: refit raw moments over all N points; per-block partials, NO atomics.
//  moments: 0=Sw 1=SxA 2=SyA 3=SxB 4=SyB 5=SxAxB 6=SxAyB 7=SyAxB 8=SyAyB
__global__ __launch_bounds__(RF_THREADS) void refit_kernel(
        const float* __restrict__ A, const float* __restrict__ B,
        const float4* __restrict__ bestp, float* __restrict__ rpart) {
    float4 h = *bestp;
    float c = h.x, s = h.y, u = h.z, v = h.w;
    float m[9];
#pragma unroll
    for (int j = 0; j < 9; ++j) m[j] = 0.f;

    int gid = blockIdx.x * RF_THREADS + threadIdx.x;
    int base = gid * RF_PTS;                          // 8 consecutive points
#pragma unroll
    for (int j = 0; j < RF_PTS; j += 2) {
        float4 a2 = ((const float4*)A)[(base + j) >> 1];   // 2 points
        float4 b2 = ((const float4*)B)[(base + j) >> 1];
#pragma unroll
        for (int k = 0; k < 2; ++k) {
            float ax = k ? a2.z : a2.x, ay = k ? a2.w : a2.y;
            float bx = k ? b2.z : b2.x, by = k ? b2.w : b2.y;
            float ex = fmaf(-c, ax, fmaf(s, ay, bx - u));
            float ey = fmaf(-c, ay, fmaf(-s, ax, by - v));
            float d2 = fmaf(ex, ex, ey * ey);
            if (d2 <= THRESH2) {
                m[0] += 1.f;
                m[1] += ax; m[2] += ay; m[3] += bx; m[4] += by;
                m[5] += ax * bx; m[6] += ax * by;
                m[7] += ay * bx; m[8] += ay * by;
            }
        }
    }
#pragma unroll
    for (int off = 32; off > 0; off >>= 1)
#pragma unroll
        for (int j = 0; j < 9; ++j) m[j] += __shfl_down(m[j], off);

    __shared__ float sred[RF_THREADS / 64][9];
    int wave = threadIdx.x >> 6, lane = threadIdx.x & 63;
    if (lane == 0)
#pragma unroll
        for (int j = 0; j < 9; ++j) sred[wave][j] = m[j];
    __syncthreads();
    if (threadIdx.x == 0) {
#pragma unroll
        for (int j = 0; j < 9; ++j) {
            float t = sred[0][j] + sred[1][j] + sred[2][j] + sred[3][j];
            rpart[blockIdx.x * 16 + j] = t;
        }
    }
}

// Kernel 6: reduce 64 refit partials (one wave) + finalize E_final.
__global__ void finalize_kernel(const float* __restrict__ rpart, float* __restrict__ out) {
    int lane = threadIdx.x;      // 64 threads = 1 wave
    float m[9];
#pragma unroll
    for (int j = 0; j < 9; ++j) m[j] = rpart[lane * 16 + j];
#pragma unroll
    for (int off = 32; off > 0; off >>= 1)
#pragma unroll
        for (int j = 0; j < 9; ++j) m[j] += __shfl_down(m[j], off);

    if (lane == 0) {
        float ws = fmaxf(m[0], 1e-8f);
        float cAx = m[1] / ws, cAy = m[2] / ws;
        float cBx = m[3] / ws, cBy = m[4] / ws;
        float sxx = (m[5] - ws * cAx * cBx) + (m[8] - ws * cAy * cBy);
        float sxy = (m[6] - ws * cAx * cBy) - (m[7] - ws * cAy * cBx);
        float rot = atan2f(sxy, sxx);
        float s, c;
        sincosf(rot, &s, &c);
        float u = cBx - (c * cAx - s * cAy);
        float v = cBy - (s * cAx + c * cAy);
        out[0] = c;   out[1] = -s;  out[2] = u;
        out[3] = s;   out[4] = c;   out[5] = v;
        out[6] = 0.f; out[7] = 0.f; out[8] = 1.f;
    }
}

extern "C" void kernel_launch(void* const* d_in, const int* in_sizes, int n_in,
                              void* d_out, int out_size, void* d_ws, size_t ws_size,
                              hipStream_t stream) {
    const float* A  = (const float*)d_in[0];   // pstA [1,N,2]
    const float* B  = (const float*)d_in[1];   // pstB [1,N,2]
    const int* sidx = (const int*)d_in[2];     // subset_idx [EPOCHS,5]
    float* out = (float*)d_out;

    char* ws = (char*)d_ws;
    float4* H       = (float4*)(ws + OFF_H);
    int*    partial = (int*)(ws + OFF_PARTIAL);
    int*    counts  = (int*)(ws + OFF_COUNTS);
    float4* best    = (float4*)(ws + OFF_BEST);
    float*  rpart   = (float*)(ws + OFF_RPART);

    hypo_kernel<<<4, 256, 0, stream>>>(A, B, sidx, H);
    score_kernel<<<SC_CHUNKS, SC_THREADS, 0, stream>>>(A, B, H, partial);
    reduce_counts_kernel<<<EPAD / 256, 256, 0, stream>>>(partial, counts);
    argmax_kernel<<<1, 256, 0, stream>>>(counts, H, out, best);
    refit_kernel<<<RF_BLOCKS, RF_THREADS, 0, stream>>>(A, B, best, rpart);
    finalize_kernel<<<1, 64, 0, stream>>>(rpart, out);
}

// Round 4
// 119.259 us; speedup vs baseline: 1.9563x; 1.0998x over previous
//
#include <hip/hip_runtime.h>
#include <math.h>

#define N_PTS   131072
#define EPOCHS  1000
#define EPAD    1024
#define THRESH2 100.0f   // dis <= 10  <=>  dis^2 <= 100

#define SC_CHUNKS  512
#define SC_PTS     (N_PTS / SC_CHUNKS)     // 256 points per chunk
#define SC_THREADS 1024                    // 1 hypothesis per thread, 16 waves/block

#define RF_BLOCKS  256
#define RF_THREADS 256                     // 2 points (1 float4) per thread

// ---------------- workspace layout (bytes) ----------------
// H        float4[1024]          @ 0         (16384)
// partial  ushort[512][1024]     @ 16384     (1048576)
// partial2 int[8][1024]          @ 1064960   (32768)
// best     float4                @ 1097728   (16)
// rpart    float[256][16]        @ 1097744   (16384)
#define OFF_H        0
#define OFF_PARTIAL  16384
#define OFF_PARTIAL2 1064960
#define OFF_BEST     1097728
#define OFF_RPART    1097744

// Kernel 1: one thread per epoch — 5-point rigid fit.
__global__ void hypo_kernel(const float* __restrict__ A, const float* __restrict__ B,
                            const int* __restrict__ idx, float4* __restrict__ H) {
    int e = blockIdx.x * blockDim.x + threadIdx.x;
    if (e >= EPOCHS) return;

    float ax[5], ay[5], bx[5], by[5];
    float cAx = 0.f, cAy = 0.f, cBx = 0.f, cBy = 0.f;
#pragma unroll
    for (int j = 0; j < 5; ++j) {
        int p = idx[e * 5 + j];
        ax[j] = A[2 * p];     ay[j] = A[2 * p + 1];
        bx[j] = B[2 * p];     by[j] = B[2 * p + 1];
        cAx += ax[j]; cAy += ay[j];
        cBx += bx[j]; cBy += by[j];
    }
    cAx *= 0.2f; cAy *= 0.2f; cBx *= 0.2f; cBy *= 0.2f;

    float sxx = 0.f, sxy = 0.f;
#pragma unroll
    for (int j = 0; j < 5; ++j) {
        float a0x = ax[j] - cAx, a0y = ay[j] - cAy;
        float b0x = bx[j] - cBx, b0y = by[j] - cBy;
        sxx += a0x * b0x + a0y * b0y;
        sxy += a0x * b0y - a0y * b0x;
    }
    float rot = atan2f(sxy, sxx);
    float s, c;
    sincosf(rot, &s, &c);
    float u = cBx - (c * cAx - s * cAy);
    float v = cBy - (s * cAx + c * cAy);
    H[e] = make_float4(c, s, u, v);
}

// Kernel 2: scoring. Thread = hypothesis (1024/block), block = point chunk.
// Point loads are block-uniform -> scalar pipe; 8 points loaded ahead per iter.
#define EVAL(AX, AY, BX, BY)                                            \
    {                                                                   \
        float ex = fmaf(-c, (AX), fmaf(s, (AY), (BX) - u));             \
        float ey = fmaf(-s, (AX), fmaf(-c, (AY), (BY) - v));            \
        float d2 = fmaf(ex, ex, ey * ey);                               \
        cnt += (d2 <= THRESH2) ? 1 : 0;                                 \
    }

__global__ __launch_bounds__(SC_THREADS) void score_kernel(
        const float* __restrict__ A, const float* __restrict__ B,
        const float4* __restrict__ H, unsigned short* __restrict__ partial) {
    int tid = threadIdx.x;
    int chunk = blockIdx.x;
    float4 h = H[tid];                       // poison for tid>=EPOCHS, discarded later
    float c = h.x, s = h.y, u = h.z, v = h.w;
    int cnt = 0;

    const float4* pA = (const float4*)A + chunk * (SC_PTS / 2);
    const float4* pB = (const float4*)B + chunk * (SC_PTS / 2);
    for (int t = 0; t < SC_PTS / 2; t += 4) {        // 8 points per iteration
        float4 a0 = pA[t + 0], a1 = pA[t + 1], a2 = pA[t + 2], a3 = pA[t + 3];
        float4 b0 = pB[t + 0], b1 = pB[t + 1], b2 = pB[t + 2], b3 = pB[t + 3];
        EVAL(a0.x, a0.y, b0.x, b0.y); EVAL(a0.z, a0.w, b0.z, b0.w);
        EVAL(a1.x, a1.y, b1.x, b1.y); EVAL(a1.z, a1.w, b1.z, b1.w);
        EVAL(a2.x, a2.y, b2.x, b2.y); EVAL(a2.z, a2.w, b2.z, b2.w);
        EVAL(a3.x, a3.y, b3.x, b3.y); EVAL(a3.z, a3.w, b3.z, b3.w);
    }
    partial[chunk * EPAD + tid] = (unsigned short)cnt;
}

// Kernel 3: stage-A count reduction: 8 groups of 64 chunks each.
__global__ void reduce_counts_kernel(const unsigned short* __restrict__ partial,
                                     int* __restrict__ partial2) {
    int gid = blockIdx.x * blockDim.x + threadIdx.x;   // 8192 threads
    int e = gid & (EPAD - 1);
    int g = gid >> 10;                                 // 0..7
    int s = 0;
    int base = g * 64;
#pragma unroll 8
    for (int k = 0; k < 64; ++k) s += partial[(base + k) * EPAD + e];
    partial2[g * EPAD + e] = s;
}

// Kernel 4: final count sum + argmax (first-index tie-break == jnp.argmax),
// emit E_best, stash best params.
__global__ void argmax_kernel(const int* __restrict__ partial2, const float4* __restrict__ H,
                              float* __restrict__ out, float4* __restrict__ best) {
    __shared__ int scnt[256];
    __shared__ int sidx[256];
    int tid = threadIdx.x;
    int bc = -2, bi = 0;
    for (int e = tid; e < EPAD; e += 256) {            // ascending: '>' keeps first max
        int cv = -1;
        if (e < EPOCHS) {
            cv = 0;
#pragma unroll
            for (int g = 0; g < 8; ++g) cv += partial2[g * EPAD + e];
        }
        if (cv > bc) { bc = cv; bi = e; }
    }
    scnt[tid] = bc; sidx[tid] = bi;
    __syncthreads();
    for (int s2 = 128; s2 > 0; s2 >>= 1) {
        if (tid < s2) {
            int c2 = scnt[tid + s2], i2 = sidx[tid + s2];
            if (c2 > scnt[tid] || (c2 == scnt[tid] && i2 < sidx[tid])) {
                scnt[tid] = c2; sidx[tid] = i2;
            }
        }
        __syncthreads();
    }
    if (tid == 0) {
        float4 h = H[sidx[0]];
        *best = h;
        out[9]  = h.x;  out[10] = -h.y; out[11] = h.z;
        out[12] = h.y;  out[13] = h.x;  out[14] = h.w;
        out[15] = 0.f;  out[16] = 0.f;  out[17] = 1.f;
    }
}

// Kernel 5: refit raw moments; 2 points (one float4) per thread; no atomics.
//  moments: 0=Sw 1=SxA 2=SyA 3=SxB 4=SyB 5=SxAxB 6=SxAyB 7=SyAxB 8=SyAyB
__global__ __launch_bounds__(RF_THREADS) void refit_kernel(
        const float* __restrict__ A, const float* __restrict__ B,
        const float4* __restrict__ bestp, float* __restrict__ rpart) {
    float4 h = *bestp;
    float c = h.x, s = h.y, u = h.z, v = h.w;
    float m[9];
#pragma unroll
    for (int j = 0; j < 9; ++j) m[j] = 0.f;

    int gid = blockIdx.x * RF_THREADS + threadIdx.x;   // 65536 threads
    float4 a2 = ((const float4*)A)[gid];               // 2 points
    float4 b2 = ((const float4*)B)[gid];
#pragma unroll
    for (int k = 0; k < 2; ++k) {
        float ax = k ? a2.z : a2.x, ay = k ? a2.w : a2.y;
        float bx = k ? b2.z : b2.x, by = k ? b2.w : b2.y;
        float ex = fmaf(-c, ax, fmaf(s, ay, bx - u));
        float ey = fmaf(-s, ax, fmaf(-c, ay, by - v));
        float d2 = fmaf(ex, ex, ey * ey);
        if (d2 <= THRESH2) {
            m[0] += 1.f;
            m[1] += ax; m[2] += ay; m[3] += bx; m[4] += by;
            m[5] += ax * bx; m[6] += ax * by;
            m[7] += ay * bx; m[8] += ay * by;
        }
    }
#pragma unroll
    for (int off = 32; off > 0; off >>= 1)
#pragma unroll
        for (int j = 0; j < 9; ++j) m[j] += __shfl_down(m[j], off);

    __shared__ float sred[RF_THREADS / 64][9];
    int wave = threadIdx.x >> 6, lane = threadIdx.x & 63;
    if (lane == 0)
#pragma unroll
        for (int j = 0; j < 9; ++j) sred[wave][j] = m[j];
    __syncthreads();
    if (threadIdx.x == 0) {
#pragma unroll
        for (int j = 0; j < 9; ++j) {
            float t = sred[0][j] + sred[1][j] + sred[2][j] + sred[3][j];
            rpart[blockIdx.x * 16 + j] = t;
        }
    }
}

// Kernel 6: reduce 256 refit partials (one wave, 4 rows/lane) + finalize E_final.
__global__ void finalize_kernel(const float* __restrict__ rpart, float* __restrict__ out) {
    int lane = threadIdx.x;      // 64 threads = 1 wave
    float m[9];
#pragma unroll
    for (int j = 0; j < 9; ++j) m[j] = 0.f;
#pragma unroll
    for (int k = 0; k < 4; ++k)
#pragma unroll
        for (int j = 0; j < 9; ++j) m[j] += rpart[(lane + 64 * k) * 16 + j];
#pragma unroll
    for (int off = 32; off > 0; off >>= 1)
#pragma unroll
        for (int j = 0; j < 9; ++j) m[j] += __shfl_down(m[j], off);

    if (lane == 0) {
        float ws = fmaxf(m[0], 1e-8f);
        float cAx = m[1] / ws, cAy = m[2] / ws;
        float cBx = m[3] / ws, cBy = m[4] / ws;
        float sxx = (m[5] - ws * cAx * cBx) + (m[8] - ws * cAy * cBy);
        float sxy = (m[6] - ws * cAx * cBy) - (m[7] - ws * cAy * cBx);
        float rot = atan2f(sxy, sxx);
        float s, c;
        sincosf(rot, &s, &c);
        float u = cBx - (c * cAx - s * cAy);
        float v = cBy - (s * cAx + c * cAy);
        out[0] = c;   out[1] = -s;  out[2] = u;
        out[3] = s;   out[4] = c;   out[5] = v;
        out[6] = 0.f; out[7] = 0.f; out[8] = 1.f;
    }
}

extern "C" void kernel_launch(void* const* d_in, const int* in_sizes, int n_in,
                              void* d_out, int out_size, void* d_ws, size_t ws_size,
                              hipStream_t stream) {
    const float* A  = (const float*)d_in[0];   // pstA [1,N,2]
    const float* B  = (const float*)d_in[1];   // pstB [1,N,2]
    const int* sidx = (const int*)d_in[2];     // subset_idx [EPOCHS,5]
    float* out = (float*)d_out;

    char* ws = (char*)d_ws;
    float4*         H        = (float4*)(ws + OFF_H);
    unsigned short* partial  = (unsigned short*)(ws + OFF_PARTIAL);
    int*            partial2 = (int*)(ws + OFF_PARTIAL2);
    float4*         best     = (float4*)(ws + OFF_BEST);
    float*          rpart    = (float*)(ws + OFF_RPART);

    hypo_kernel<<<4, 256, 0, stream>>>(A, B, sidx, H);
    score_kernel<<<SC_CHUNKS, SC_THREADS, 0, stream>>>(A, B, H, partial);
    reduce_counts_kernel<<<32, 256, 0, stream>>>(partial, partial2);
    argmax_kernel<<<1, 256, 0, stream>>>(partial2, H, out, best);
    refit_kernel<<<RF_BLOCKS, RF_THREADS, 0, stream>>>(A, B, best, rpart);
    finalize_kernel<<<1, 64, 0, stream>>>(rpart, out);
}